// Round 4
// baseline (477.126 us; speedup 1.0000x reference)
//
#include <hip/hip_runtime.h>
#include <cstdint>
#include <cstddef>

#define EPSV 1e-5f

typedef __bf16 bf16x8 __attribute__((ext_vector_type(8)));
typedef float f32x4 __attribute__((ext_vector_type(4)));

__device__ __forceinline__ unsigned short f2bf(float f) {
  unsigned int u = __float_as_uint(f);
  u += 0x7FFFu + ((u >> 16) & 1u);   // round-to-nearest-even
  return (unsigned short)(u >> 16);
}

__device__ __forceinline__ float bf2f(unsigned short h) {
  return __uint_as_float(((unsigned int)h) << 16);
}

__device__ __forceinline__ void async_copy16(const void* src, void* dst_lds) {
  __builtin_amdgcn_global_load_lds(
      (const __attribute__((address_space(1))) void*)src,
      (__attribute__((address_space(3))) void*)dst_lds, 16, 0, 0);
}

// ---------------- prep: weight transpose + global-mean BN + mask stats -----
// blocks [0,8192): transpose W1/W2 (fp32 KxN) -> Wt (bf16 NxK)
// blocks [8192,40960): feat_global = mean(x_global,hw) + BN -> out[:, :2048]
// blocks [40960,41024): mask downsample / counts / drop
__global__ __launch_bounds__(256) void prep(
    const float* __restrict__ W1, const float* __restrict__ W2,
    unsigned short* __restrict__ Wt1, unsigned short* __restrict__ Wt2,
    const float* __restrict__ xg, const float* __restrict__ gb_g,
    const float* __restrict__ gb_b, const float* __restrict__ gb_rm,
    const float* __restrict__ gb_rv, float* __restrict__ out,
    const int* __restrict__ mask, int* __restrict__ partid,
    float* __restrict__ invden, int* __restrict__ dropm1) {
  int blk = blockIdx.x;
  if (blk < 8192) {
    int z = blk >> 12;
    int rem = blk & 4095;
    int by = rem >> 6, bx = rem & 63;
    const float* W = z ? W2 : W1;
    unsigned short* Wt = z ? Wt2 : Wt1;
    __shared__ float tile[32][33];
    int tx = threadIdx.x & 31;
    int ty = threadIdx.x >> 5;  // 0..7
    int k0 = by * 32, n0 = bx * 32;
#pragma unroll
    for (int i = 0; i < 32; i += 8)
      tile[ty + i][tx] = W[(size_t)(k0 + ty + i) * 2048 + n0 + tx];
    __syncthreads();
#pragma unroll
    for (int i = 0; i < 32; i += 8)
      Wt[(size_t)(n0 + ty + i) * 2048 + k0 + tx] = f2bf(tile[tx][ty + i]);
  } else if (blk < 40960) {
    int gw = (blk - 8192) * 4 + (threadIdx.x >> 6);  // (b,c) pair per wave
    int lane = threadIdx.x & 63;
    float4 v = ((const float4*)(xg + (size_t)gw * 256))[lane];
    float s = v.x + v.y + v.z + v.w;
#pragma unroll
    for (int o = 32; o > 0; o >>= 1) s += __shfl_xor(s, o, 64);
    if (lane == 0) {
      int b = gw >> 11, c = gw & 2047;
      float m = s * (1.f / 256.f);
      out[(size_t)b * 43008 + c] =
          (m - gb_rm[c]) / sqrtf(gb_rv[c] + EPSV) * gb_g[c] + gb_b[c];
    }
  } else {
    int b = blk - 40960;
    int t = threadIdx.x;
    int h = t >> 4, w = t & 15;
    int m = mask[(size_t)b * 65536 + h * 4096 + w * 16];
    partid[b * 256 + t] = m;
    __shared__ int cnt[10];
    if (t < 10) cnt[t] = 0;
    __syncthreads();
    atomicAdd(&cnt[m], 1);
    __syncthreads();
    if (t == 0) {
      int dp = 0;
      for (int p = 8; p >= 0; p--)
        if (cnt[p + 1] > 0) dp = p;
      dropm1[b] = dp;
    }
    if (t < 9) invden[b * 9 + t] = 1.f / ((float)cnt[t + 1] + 1e-8f);
  }
}

// ---------------- part-pooling via MFMA + fused adj-mix --------------------
// Produces A1'[(br*64+b)*9+p, c] = sum_q adj[b,p,q] * s_br[q,c]  (bf16),
// where s_mask[q]=pool[q]*inv[q], s_self[q]= (q==drop-1 ? 0 : s_mask[q]).
__global__ __launch_bounds__(256) void kpool_mfma(
    const float* __restrict__ x, const int* __restrict__ partid,
    const float* __restrict__ invden, const int* __restrict__ dropm1,
    const float* __restrict__ adj, unsigned short* __restrict__ A1) {
  __shared__ unsigned short As[64 * 264];
  __shared__ unsigned short Bs[16 * 264];
  __shared__ int pid[256];
  __shared__ float sbuf[4][4][16][4];  // [wave][quad][q][ch]
  const int t = threadIdx.x;
  const int b = blockIdx.y;
  const int c0 = blockIdx.x * 64;

  pid[t] = partid[b * 256 + t];

  const float4* xgp = (const float4*)(x + ((size_t)(b * 2048 + c0)) * 256);
#pragma unroll
  for (int it = 0; it < 16; it++) {
    int idx = t + it * 256;
    float4 v = xgp[idx];
    int row = idx >> 6, sc = (idx & 63) * 4;
    ushort4 h;
    h.x = f2bf(v.x); h.y = f2bf(v.y); h.z = f2bf(v.z); h.w = f2bf(v.w);
    *(ushort4*)&As[row * 264 + sc] = h;
  }
  __syncthreads();
  {
    int p = t >> 4, s0 = (t & 15) * 16;
#pragma unroll
    for (int j = 0; j < 16; j++)
      Bs[p * 264 + s0 + j] =
          (pid[s0 + j] == p + 1) ? (unsigned short)0x3F80 : (unsigned short)0;
  }
  __syncthreads();

  const int wave = t >> 6;
  const int l16 = t & 15;
  const int quad = (t & 63) >> 4;
  f32x4 acc = (f32x4){0.f, 0.f, 0.f, 0.f};
#pragma unroll
  for (int ks = 0; ks < 8; ks++) {
    bf16x8 a = *(const bf16x8*)&As[(wave * 16 + l16) * 264 + ks * 32 + quad * 8];
    bf16x8 bf = *(const bf16x8*)&Bs[l16 * 264 + ks * 32 + quad * 8];
    acc = __builtin_amdgcn_mfma_f32_16x16x32_bf16(a, bf, acc, 0, 0, 0);
  }

  // s[q][ch] exchange within (wave,quad)
  {
    float inv = (l16 < 9) ? invden[b * 9 + l16] : 0.f;
    sbuf[wave][quad][l16][0] = acc[0] * inv;
    sbuf[wave][quad][l16][1] = acc[1] * inv;
    sbuf[wave][quad][l16][2] = acc[2] * inv;
    sbuf[wave][quad][l16][3] = acc[3] * inv;
  }
  __syncthreads();

  if (l16 < 9) {
    int p = l16;
    int dm1 = dropm1[b];
    const float* ap = adj + b * 81 + p * 9;
    float om[4] = {0.f, 0.f, 0.f, 0.f};
#pragma unroll
    for (int q = 0; q < 9; q++) {
      float aq = ap[q];
#pragma unroll
      for (int r = 0; r < 4; r++) om[r] += aq * sbuf[wave][quad][q][r];
    }
    float ad = ap[dm1];
    float os[4];
#pragma unroll
    for (int r = 0; r < 4; r++) os[r] = om[r] - ad * sbuf[wave][quad][dm1][r];

    int cbase = c0 + wave * 16 + quad * 4;
    ushort4 hm, hs;
    hm.x = f2bf(om[0]); hm.y = f2bf(om[1]);
    hm.z = f2bf(om[2]); hm.w = f2bf(om[3]);
    hs.x = f2bf(os[0]); hs.y = f2bf(os[1]);
    hs.z = f2bf(os[2]); hs.w = f2bf(os[3]);
    *(ushort4*)&A1[(size_t)(b * 9 + p) * 2048 + cbase] = hm;
    *(ushort4*)&A1[(size_t)((64 + b) * 9 + p) * 2048 + cbase] = hs;
  }
}

// ---------------- GEMM + fused bias/BN/ReLU epilogue -----------------------
// S[m,n] = A[m,:] . Wt[n,:] ; v = relu(bn(S + bias)) ;
// LAYER 1: write bf16 to Aout[m*2048+n].
// LAYER 2: write fp32 to out[b*43008 + (br?24576:6144) + p*2048 + n],
//          m = (br*64+b)*9 + p.
#define GK 2048
template <int LAYER>
__global__ __launch_bounds__(256) void gemm_fused(
    const unsigned short* __restrict__ A, const unsigned short* __restrict__ Bt,
    const float* __restrict__ bias, const float* __restrict__ g,
    const float* __restrict__ be, const float* __restrict__ rm,
    const float* __restrict__ rv, unsigned short* __restrict__ Aout,
    float* __restrict__ out) {
  __shared__ unsigned short As[2][128 * 64];
  __shared__ unsigned short Bs[2][128 * 64];
  const int tid = threadIdx.x;
  const int lane = tid & 63;
  const int wave = tid >> 6;
  const int wm = (wave >> 1) << 6;
  const int wn = (wave & 1) << 6;
  const int quad = lane >> 4;
  const int l16 = lane & 15;
  const int by = blockIdx.y;
  const int bx = blockIdx.x;

  const unsigned short* Ag = A + (size_t)by * 128 * GK;
  const unsigned short* Bg = Bt + (size_t)bx * 128 * GK;

  f32x4 acc[4][4];
#pragma unroll
  for (int i = 0; i < 4; i++)
#pragma unroll
    for (int j = 0; j < 4; j++) acc[i][j] = (f32x4){0.f, 0.f, 0.f, 0.f};

  int srow[4], scol[4];
#pragma unroll
  for (int s = 0; s < 4; s++) {
    int idx = tid + s * 256;
    srow[s] = idx >> 3;
    scol[s] = ((idx & 7) ^ (srow[s] & 7)) * 8;
  }

#define STAGE(buf, kk)                                                        \
  do {                                                                        \
    _Pragma("unroll") for (int s = 0; s < 4; s++) {                           \
      int idx = tid + s * 256;                                                \
      async_copy16(Ag + (size_t)srow[s] * GK + (kk) + scol[s],                \
                   &As[buf][idx * 8]);                                        \
    }                                                                         \
    _Pragma("unroll") for (int s = 0; s < 4; s++) {                           \
      int idx = tid + s * 256;                                                \
      async_copy16(Bg + (size_t)srow[s] * GK + (kk) + scol[s],                \
                   &Bs[buf][idx * 8]);                                        \
    }                                                                         \
  } while (0)

  STAGE(0, 0);
  asm volatile("s_waitcnt vmcnt(0)" ::: "memory");
  __syncthreads();

  for (int it = 0; it < 32; it++) {
    const int cur = it & 1;
    if (it < 31) STAGE(cur ^ 1, (it + 1) * 64);

#pragma unroll
    for (int ks = 0; ks < 2; ks++) {
      bf16x8 af[4], bfr[4];
#pragma unroll
      for (int i = 0; i < 4; i++) {
        int row = wm + i * 16 + l16;
        int slot = row * 8 + ((ks * 4 + quad) ^ (row & 7));
        af[i] = *(const bf16x8*)&As[cur][slot * 8];
      }
#pragma unroll
      for (int j = 0; j < 4; j++) {
        int row = wn + j * 16 + l16;
        int slot = row * 8 + ((ks * 4 + quad) ^ (row & 7));
        bfr[j] = *(const bf16x8*)&Bs[cur][slot * 8];
      }
#pragma unroll
      for (int i = 0; i < 4; i++)
#pragma unroll
        for (int j = 0; j < 4; j++)
          acc[i][j] = __builtin_amdgcn_mfma_f32_16x16x32_bf16(
              af[i], bfr[j], acc[i][j], 0, 0, 0);
    }

    if (it < 31) {
      asm volatile("s_waitcnt vmcnt(0)" ::: "memory");
      __syncthreads();
    }
  }

#pragma unroll
  for (int i = 0; i < 4; i++)
#pragma unroll
    for (int r = 0; r < 4; r++) {
      int m = by * 128 + wm + i * 16 + quad * 4 + r;
      int grp = m / 9;          // (branch*64 + b)
      int p = m - grp * 9;
#pragma unroll
      for (int j = 0; j < 4; j++) {
        int n = bx * 128 + wn + j * 16 + l16;
        int f = p * 2048 + n;
        float v = acc[i][j][r] + bias[n];
        v = (v - rm[f]) / sqrtf(rv[f] + EPSV) * g[f] + be[f];
        v = fmaxf(v, 0.f);
        if (LAYER == 1) {
          Aout[(size_t)m * 2048 + n] = f2bf(v);
        } else {
          int b = grp & 63;
          size_t base = (size_t)b * 43008 + ((grp >> 6) ? 24576 : 6144);
          out[base + f] = v;
        }
      }
    }
}

// ---------------- kadj2: A2' = adj . A2  (bf16, tiny) ----------------------
__global__ __launch_bounds__(256) void kadj2(
    const unsigned short* __restrict__ A2, const float* __restrict__ adj,
    unsigned short* __restrict__ A2p) {
  int t = blockIdx.x * 256 + threadIdx.x;  // over 128*2048
  int d = t & 2047;
  int bb = t >> 11;
  int b = bb & 63;
  float s[9];
#pragma unroll
  for (int q = 0; q < 9; q++) s[q] = bf2f(A2[(size_t)(bb * 9 + q) * 2048 + d]);
  const float* ap = adj + b * 81;
#pragma unroll
  for (int p = 0; p < 9; p++) {
    float o = 0.f;
#pragma unroll
    for (int q = 0; q < 9; q++) o += ap[p * 9 + q] * s[q];
    A2p[(size_t)(bb * 9 + p) * 2048 + d] = f2bf(o);
  }
}

// ---------------- kfinal: per-branch mean over p + BN ----------------------
__global__ __launch_bounds__(256) void kfinal(
    const float* __restrict__ gn_g, const float* __restrict__ gn_b,
    const float* __restrict__ gn_rm, const float* __restrict__ gn_rv,
    float* __restrict__ out) {
  int t = blockIdx.x * 256 + threadIdx.x;  // over 128*2048
  int d = t & 2047;
  int grp = t >> 11;  // branch*64 + b
  int b = grp & 63;
  int br = grp >> 6;
  const float* src = out + (size_t)b * 43008 + (br ? 24576 : 6144) + d;
  float s = 0.f;
#pragma unroll
  for (int p = 0; p < 9; p++) s += src[p * 2048];
  s *= (1.f / 9.f);
  out[(size_t)b * 43008 + (br ? 4096 : 2048) + d] =
      (s - gn_rm[d]) / sqrtf(gn_rv[d] + EPSV) * gn_g[d] + gn_b[d];
}

extern "C" void kernel_launch(void* const* d_in, const int* in_sizes, int n_in,
                              void* d_out, int out_size, void* d_ws,
                              size_t ws_size, hipStream_t stream) {
  const float* x_global = (const float*)d_in[0];
  const float* x_gcn = (const float*)d_in[1];
  const int* mask = (const int*)d_in[2];
  const float* adj = (const float*)d_in[3];
  const float* W1 = (const float*)d_in[4];
  const float* b1 = (const float*)d_in[5];
  const float* g1 = (const float*)d_in[6];
  const float* be1 = (const float*)d_in[7];
  const float* rm1 = (const float*)d_in[8];
  const float* rv1 = (const float*)d_in[9];
  const float* W2 = (const float*)d_in[10];
  const float* b2 = (const float*)d_in[11];
  const float* g2 = (const float*)d_in[12];
  const float* be2 = (const float*)d_in[13];
  const float* rm2 = (const float*)d_in[14];
  const float* rv2 = (const float*)d_in[15];
  const float* gb_g = (const float*)d_in[16];
  const float* gb_b = (const float*)d_in[17];
  const float* gb_rm = (const float*)d_in[18];
  const float* gb_rv = (const float*)d_in[19];
  const float* gn_g = (const float*)d_in[20];
  const float* gn_b = (const float*)d_in[21];
  const float* gn_rm = (const float*)d_in[22];
  const float* gn_rv = (const float*)d_in[23];
  float* out = (float*)d_out;

  char* ws = (char*)d_ws;
  int* partid = (int*)(ws);                                  // 64 KB
  float* invden = (float*)(ws + 65536);
  int* dropm1 = (int*)(ws + 67840);
  unsigned short* A1 = (unsigned short*)(ws + 131072);       // 4.5 MB
  unsigned short* A2 = (unsigned short*)(ws + 4849664);      // 4.5 MB
  unsigned short* A2p = (unsigned short*)(ws + 9568256);     // 4.5 MB
  unsigned short* Wt1 = (unsigned short*)(ws + 14286848);    // 8 MB
  unsigned short* Wt2 = (unsigned short*)(ws + 22675456);    // 8 MB

  prep<<<41024, 256, 0, stream>>>(W1, W2, Wt1, Wt2, x_global, gb_g, gb_b,
                                  gb_rm, gb_rv, out, mask, partid, invden,
                                  dropm1);
  kpool_mfma<<<dim3(32, 64), 256, 0, stream>>>(x_gcn, partid, invden, dropm1,
                                               adj, A1);
  gemm_fused<1><<<dim3(16, 9), 256, 0, stream>>>(A1, Wt1, b1, g1, be1, rm1,
                                                 rv1, A2, nullptr);
  kadj2<<<1024, 256, 0, stream>>>(A2, adj, A2p);
  gemm_fused<2><<<dim3(16, 9), 256, 0, stream>>>(A2p, Wt2, b2, g2, be2, rm2,
                                                 rv2, nullptr, out);
  kfinal<<<1024, 256, 0, stream>>>(gn_g, gn_b, gn_rm, gn_rv, out);
}